// Round 1
// baseline (151.791 us; speedup 1.0000x reference)
//
#include <hip/hip_runtime.h>
#include <math.h>

namespace {
constexpr int K = 15;
constexpr int FD = 128;
constexpr int FS = 160;
constexpr int OV = 40;
constexpr int NFRAMES = 500;
constexpr int NSAMP = NFRAMES * FS;   // 80000
constexpr float C_CONST = 0.11512925464970229f;
constexpr float LOG_GAIN_LIMIT = 10.0f * C_CONST;
constexpr float GAIN_A = 6.0f * C_CONST;
constexpr int WIN_CUR = FS + K - 1;   // 174 samples for current-frame conv (l=0..159)
constexpr int WIN_PREV = OV + K - 1;  // 54 samples for prev-frame tail conv (l=160..199)
constexpr float PI_F = 3.14159265358979323846f;
}

__global__ __launch_bounds__(256)
void comb_fused(const float* __restrict__ x,      // (B, NSAMP)
                const float* __restrict__ feat,   // (B, NF, FD)
                const int*   __restrict__ lags,   // (B, NF)
                const float* __restrict__ ck_w,   // (K, FD)
                const float* __restrict__ ck_b,   // (K)
                const float* __restrict__ fg_w,   // (FD)
                const float* __restrict__ fg_b,   // (1)
                const float* __restrict__ gg_w,   // (FD)
                const float* __restrict__ gg_b,   // (1)
                float* __restrict__ out,          // (B, NSAMP)
                int nframes_total)
{
    const int bid = blockIdx.x;
    if (bid >= nframes_total) return;
    const int b = bid / NFRAMES;
    const int f = bid - b * NFRAMES;
    const int tid = threadIdx.x;
    const int lane = tid & 63;
    const int wave = tid >> 6;

    __shared__ float sf[2][FD];        // features: [0]=cur frame f, [1]=prev frame f-1
    __shared__ float sdots[2][17];     // 15 kernel taps + fg + gg (raw, bias added)
    __shared__ float skern[2][K];
    __shared__ float skscale[2];       // ggain*gain*inv_norm
    __shared__ float spscale[2];       // ggain
    __shared__ float swin[WIN_CUR + WIN_PREV];
    __shared__ float snv[FS + OV];     // new_chunk values: [0..159]=cur, [160..199]=prev tail

    const float* xb = x + (size_t)b * NSAMP;

    // ---- stage features (cur + prev) to LDS ----
    {
        const int fr = tid >> 7;   // 0 = current, 1 = previous
        const int j  = tid & 127;
        float v = 0.0f;
        if (fr == 0)
            v = feat[((size_t)b * NFRAMES + f) * FD + j];
        else if (f > 0)
            v = feat[((size_t)b * NFRAMES + (f - 1)) * FD + j];
        sf[fr][j] = v;
    }
    __syncthreads();

    // ---- 34 dot products (17 per frame), one per wave round-robin ----
    for (int d = wave; d < 34; d += 4) {
        const int fr = d / 17;
        const int kk = d - fr * 17;
        const float* w = (kk < K) ? (ck_w + (size_t)kk * FD)
                                  : ((kk == K) ? fg_w : gg_w);
        float s = sf[fr][lane] * w[lane] + sf[fr][lane + 64] * w[lane + 64];
        #pragma unroll
        for (int off = 32; off > 0; off >>= 1)
            s += __shfl_xor(s, off, 64);
        if (lane == 0) {
            const float bias = (kk < K) ? ck_b[kk] : ((kk == K) ? fg_b[0] : gg_b[0]);
            sdots[fr][kk] = s + bias;
        }
    }

    // ---- stage x windows to LDS (overlaps with dot reductions across waves) ----
    const int lag_c  = lags[b * NFRAMES + f];
    const int base_c = f * FS - lag_c - 7;           // x-index of xx_cur[0]
    int base_p = 0;
    if (f > 0) {
        const int lag_p = lags[b * NFRAMES + f - 1];
        base_p = f * FS - lag_p - 7;                 // x-index of xx_prev[160]
    }
    __syncthreads();   // dots done (needed before param calc); windows can now fill

    for (int i = tid; i < WIN_CUR + WIN_PREV; i += 256) {
        int idx;
        bool live = true;
        if (i < WIN_CUR) {
            idx = base_c + i;
        } else {
            idx = base_p + (i - WIN_CUR);
            live = (f > 0);
        }
        float v = 0.0f;
        if (live && idx >= 0 && idx < NSAMP) v = xb[idx];
        swin[i] = v;
    }

    // ---- per-frame params (normalization + gains): 2 threads ----
    if (tid < 2) {
        const int fr = tid;
        float n2 = 0.0f;
        #pragma unroll
        for (int k = 0; k < K; ++k) {
            const float v = sdots[fr][k];
            n2 += v * v;
            skern[fr][k] = v;
        }
        const float inv  = 1.0f / (1e-6f + sqrtf(n2));
        const float gain = expf(-fmaxf(sdots[fr][K], 0.0f) + LOG_GAIN_LIMIT);
        const float ggain = expf(GAIN_A * tanhf(sdots[fr][K + 1]));
        skscale[fr] = ggain * gain * inv;
        spscale[fr] = ggain;
    }
    __syncthreads();

    // ---- conv + new_chunk ----
    if (tid < FS + OV) {
        float c = 0.0f;
        float val;
        if (tid < FS) {
            #pragma unroll
            for (int k = 0; k < K; ++k)
                c += swin[tid + k] * skern[0][k];
            val = skscale[0] * c + spscale[0] * xb[f * FS + tid];
        } else if (f > 0) {
            const int t0 = tid - FS;   // 0..39
            #pragma unroll
            for (int k = 0; k < K; ++k)
                c += swin[WIN_CUR + t0 + k] * skern[1][k];
            // pt_prev[160+t0] == x[f*FS + t0]
            val = skscale[1] * c + spscale[1] * xb[f * FS + t0];
        } else {
            val = 0.0f;
        }
        snv[tid] = val;
    }
    __syncthreads();

    // ---- crossfade head with previous tail, store ----
    if (tid < FS) {
        float o = snv[tid];
        if (tid < OV) {
            const float w2 = 0.5f + 0.5f * cosf(((float)tid + 0.5f) * (PI_F / OV));
            o = o * (1.0f - w2) + snv[FS + tid] * w2;   // win1 = 1 - win2
        }
        out[(size_t)b * NSAMP + f * FS + tid] = o;
    }
}

extern "C" void kernel_launch(void* const* d_in, const int* in_sizes, int n_in,
                              void* d_out, int out_size, void* d_ws, size_t ws_size,
                              hipStream_t stream) {
    const float* x    = (const float*)d_in[0];
    const float* feat = (const float*)d_in[1];
    const int*   lags = (const int*)d_in[2];
    const float* ck_w = (const float*)d_in[3];
    const float* ck_b = (const float*)d_in[4];
    const float* fg_w = (const float*)d_in[5];
    const float* fg_b = (const float*)d_in[6];
    const float* gg_w = (const float*)d_in[7];
    const float* gg_b = (const float*)d_in[8];
    float* out = (float*)d_out;

    const int B = in_sizes[2] / NFRAMES;   // lags has B*NF elements
    const int nblocks = B * NFRAMES;
    comb_fused<<<dim3(nblocks), dim3(256), 0, stream>>>(
        x, feat, lags, ck_w, ck_b, fg_w, fg_b, gg_w, gg_b, out, nblocks);
}

// Round 2
// 108.044 us; speedup vs baseline: 1.4049x; 1.4049x over previous
//
#include <hip/hip_runtime.h>
#include <math.h>

namespace {
constexpr int K = 15;
constexpr int FD = 128;
constexpr int FS = 160;
constexpr int OV = 40;
constexpr int NFRAMES = 500;
constexpr int NSAMP = NFRAMES * FS;   // 80000
constexpr float C_CONST = 0.11512925464970229f;
constexpr float LOG_GAIN_LIMIT = 10.0f * C_CONST;
constexpr float GAIN_A = 6.0f * C_CONST;
constexpr int FPB = 10;               // frames per block (500 % 10 == 0)
constexpr int NFR = FPB + 1;          // + previous frame for overlap-add tail
constexpr int WIN = FS + OV + K - 1;  // 214 contiguous window samples per frame
constexpr int SFSTR = 132;            // padded feature row stride (bank-conflict-free float4)
constexpr float PI_F = 3.14159265358979323846f;
}

__global__ __launch_bounds__(256)
void comb_fused(const float* __restrict__ x,      // (B, NSAMP)
                const float* __restrict__ feat,   // (B, NF, FD)
                const int*   __restrict__ lags,   // (B, NF)
                const float* __restrict__ ck_w,   // (K, FD)
                const float* __restrict__ ck_b,   // (K)
                const float* __restrict__ fg_w,   // (FD)
                const float* __restrict__ fg_b,   // (1)
                const float* __restrict__ gg_w,   // (FD)
                const float* __restrict__ gg_b,   // (1)
                float* __restrict__ out)          // (B, NSAMP)
{
    const int tid = threadIdx.x;
    const int bid = blockIdx.x;
    const int b   = bid / (NFRAMES / FPB);
    const int blk = bid - b * (NFRAMES / FPB);
    const int f0  = blk * FPB;

    __shared__ float sf[NFR][SFSTR];    // features, fr=0 is prev frame f0-1
    __shared__ float swin[NFR][WIN];    // per-frame 214-sample x window
    __shared__ float sdots[NFR][17];    // raw dot products (+bias)
    __shared__ float sfk[NFR][16];      // [0..14]=kscale*kern, [15]=pscale(ggain)
    __shared__ int   sbase[NFR];
    __shared__ int   svalid[NFR];

    const float* xb = x + (size_t)b * NSAMP;

    // ---- phase 1: bases + feature staging ----
    if (tid < NFR) {
        const int pf = f0 - 1 + tid;
        const int valid = (pf >= 0) ? 1 : 0;
        svalid[tid] = valid;
        sbase[tid]  = valid ? (pf * FS - lags[b * NFRAMES + pf] - 7) : 0;
    }
    for (int i = tid; i < NFR * (FD / 4); i += 256) {
        const int fr = i >> 5;           // /32
        const int e4 = i & 31;
        const int pf = f0 - 1 + fr;
        float4 v = make_float4(0.f, 0.f, 0.f, 0.f);
        if (pf >= 0)
            v = ((const float4*)feat)[((size_t)b * NFRAMES + pf) * (FD / 4) + e4];
        *(float4*)&sf[fr][e4 * 4] = v;
    }
    __syncthreads();

    // ---- phase 2a: window staging (global, mostly coalesced, clamped) ----
    for (int i = tid; i < NFR * WIN; i += 256) {
        const int fr = i / WIN;
        const int l  = i - fr * WIN;
        const int idx = sbase[fr] + l;
        float v = 0.f;
        if (svalid[fr] && idx >= 0 && idx < NSAMP) v = xb[idx];
        swin[fr][l] = v;
    }

    // ---- phase 2b: dot products, one thread per (frame, dot) ----
    if (tid < NFR * 17) {
        const int fr = tid / 17;
        const int j  = tid - fr * 17;
        const float* wrow = (j < K) ? (ck_w + (size_t)j * FD)
                                    : ((j == K) ? fg_w : gg_w);
        const float4* w4 = (const float4*)wrow;
        const float4* f4 = (const float4*)&sf[fr][0];
        float4 acc = make_float4(0.f, 0.f, 0.f, 0.f);
        #pragma unroll
        for (int i = 0; i < FD / 4; ++i) {
            const float4 a = f4[i];
            const float4 w = w4[i];
            acc.x += a.x * w.x; acc.y += a.y * w.y;
            acc.z += a.z * w.z; acc.w += a.w * w.w;
        }
        const float bias = (j < K) ? ck_b[j] : ((j == K) ? fg_b[0] : gg_b[0]);
        sdots[fr][j] = acc.x + acc.y + acc.z + acc.w + bias;
    }
    __syncthreads();

    // ---- phase 3: per-frame params ----
    if (tid < NFR) {
        const int fr = tid;
        if (!svalid[fr]) {
            #pragma unroll
            for (int k = 0; k < 16; ++k) sfk[fr][k] = 0.f;   // zero prev => tail 0
        } else {
            float kern[K];
            float n2 = 0.f;
            #pragma unroll
            for (int k = 0; k < K; ++k) {
                kern[k] = sdots[fr][k];
                n2 += kern[k] * kern[k];
            }
            const float inv   = 1.f / (1e-6f + sqrtf(n2));
            const float gain  = expf(-fmaxf(sdots[fr][K], 0.f) + LOG_GAIN_LIMIT);
            const float ggain = expf(GAIN_A * tanhf(sdots[fr][K + 1]));
            const float ks    = ggain * gain * inv;
            #pragma unroll
            for (int k = 0; k < K; ++k) sfk[fr][k] = ks * kern[k];
            sfk[fr][15] = ggain;
        }
    }
    __syncthreads();

    // ---- phase 4: conv + crossfade + store (coalesced) ----
    const int obase = f0 * FS;
    for (int o = tid; o < FPB * FS; o += 256) {
        const int frl = o / FS;          // 0..FPB-1
        const int t   = o - frl * FS;    // 0..159
        const int fr  = frl + 1;         // window/param index
        const float pt = xb[obase + o];  // pass-through, shared by cur & prev tail
        float c = 0.f;
        #pragma unroll
        for (int k = 0; k < K; ++k)
            c += swin[fr][t + k] * sfk[fr][k];
        float val = c + sfk[fr][15] * pt;
        if (t < OV) {
            float ct = 0.f;
            #pragma unroll
            for (int k = 0; k < K; ++k)
                ct += swin[fr - 1][FS + t + k] * sfk[fr - 1][k];
            const float tail = ct + sfk[fr - 1][15] * pt;
            const float w2 = 0.5f + 0.5f * cosf(((float)t + 0.5f) * (PI_F / OV));
            val = val * (1.f - w2) + tail * w2;
        }
        out[(size_t)b * NSAMP + obase + o] = val;
    }
}

extern "C" void kernel_launch(void* const* d_in, const int* in_sizes, int n_in,
                              void* d_out, int out_size, void* d_ws, size_t ws_size,
                              hipStream_t stream) {
    const float* x    = (const float*)d_in[0];
    const float* feat = (const float*)d_in[1];
    const int*   lags = (const int*)d_in[2];
    const float* ck_w = (const float*)d_in[3];
    const float* ck_b = (const float*)d_in[4];
    const float* fg_w = (const float*)d_in[5];
    const float* fg_b = (const float*)d_in[6];
    const float* gg_w = (const float*)d_in[7];
    const float* gg_b = (const float*)d_in[8];
    float* out = (float*)d_out;

    const int B = in_sizes[0] / NSAMP;
    const int nblocks = B * (NFRAMES / FPB);
    comb_fused<<<dim3(nblocks), dim3(256), 0, stream>>>(
        x, feat, lags, ck_w, ck_b, fg_w, fg_b, gg_w, gg_b, out);
}

// Round 3
// 106.391 us; speedup vs baseline: 1.4267x; 1.0155x over previous
//
#include <hip/hip_runtime.h>
#include <math.h>

namespace {
constexpr int K = 15;
constexpr int FD = 128;
constexpr int FS = 160;
constexpr int OV = 40;
constexpr int NFRAMES = 500;
constexpr int NSAMP = NFRAMES * FS;   // 80000
constexpr float C_CONST = 0.11512925464970229f;
constexpr float LOG_GAIN_LIMIT = 10.0f * C_CONST;
constexpr float GAIN_A = 6.0f * C_CONST;
constexpr int FPB = 10;               // frames per block (500 % 10 == 0)
constexpr int NFR = FPB + 1;          // + previous frame for overlap-add tail
constexpr int NW4 = 55;               // float4 window loads per frame (220 floats >= 216 needed)
constexpr int WINA = 220;             // window row allocation (floats, 16B-aligned rows)
constexpr int SFSTR = 132;            // padded feature row stride
constexpr float PI_F = 3.14159265358979323846f;
}

__global__ __launch_bounds__(256)
void comb_fused(const float* __restrict__ x,      // (B, NSAMP)
                const float* __restrict__ feat,   // (B, NF, FD)
                const int*   __restrict__ lags,   // (B, NF)
                const float* __restrict__ ck_w,   // (K, FD)
                const float* __restrict__ ck_b,   // (K)
                const float* __restrict__ fg_w,   // (FD)
                const float* __restrict__ fg_b,   // (1)
                const float* __restrict__ gg_w,   // (FD)
                const float* __restrict__ gg_b,   // (1)
                float* __restrict__ out)          // (B, NSAMP)
{
    const int tid = threadIdx.x;
    const int bid = blockIdx.x;
    const int b   = bid / (NFRAMES / FPB);
    const int blk = bid - b * (NFRAMES / FPB);
    const int f0  = blk * FPB;

    __shared__ __align__(16) float sf[NFR][SFSTR];   // features, fr=0 is frame f0-1
    __shared__ __align__(16) float swin[NFR][WINA];  // swin[fr][l] = x[base_fr + l]
    __shared__ float sdots[NFR][17];                 // raw dots (+bias)
    __shared__ __align__(16) float sfk[NFR][16];     // [0..14]=kscale*kern, [15]=ggain
    __shared__ __align__(16) float swin2[OV + 8];    // crossfade window (win2)

    const float* xb = x + (size_t)b * NSAMP;

    // ---- phase A: stage features + windows (pure global->LDS, no deps) ----
    for (int i = tid; i < NFR * (FD / 4); i += 256) {
        const int fr = i >> 5;           // /32
        const int e4 = i & 31;
        const int pf = f0 - 1 + fr;
        float4 v = make_float4(0.f, 0.f, 0.f, 0.f);
        if (pf >= 0)
            v = ((const float4*)feat)[((size_t)b * NFRAMES + pf) * (FD / 4) + e4];
        *(float4*)&sf[fr][e4 * 4] = v;
    }

    for (int i = tid; i < NFR * NW4; i += 256) {
        const int fr = i / NW4;
        const int m  = i - fr * NW4;
        const int pf = f0 - 1 + fr;
        float4 v = make_float4(0.f, 0.f, 0.f, 0.f);
        if (pf >= 0) {
            const int base = pf * FS - lags[b * NFRAMES + pf] - 7;
            const int idx  = base + 4 * m;   // 4B-aligned global float4 load is legal on gfx9
            if (idx >= 0 && idx + 3 < NSAMP) {
                v = *(const float4*)(xb + idx);
            } else {
                if (idx     >= 0 && idx     < NSAMP) v.x = xb[idx];
                if (idx + 1 >= 0 && idx + 1 < NSAMP) v.y = xb[idx + 1];
                if (idx + 2 >= 0 && idx + 2 < NSAMP) v.z = xb[idx + 2];
                if (idx + 3 >= 0 && idx + 3 < NSAMP) v.w = xb[idx + 3];
            }
        }
        *(float4*)&swin[fr][4 * m] = v;
    }

    if (tid < OV)
        swin2[tid] = 0.5f + 0.5f * cosf(((float)tid + 0.5f) * (PI_F / OV));
    __syncthreads();

    // ---- phase B: 17 dots per frame, one thread each (187 threads) ----
    if (tid < NFR * 17) {
        const int fr = tid / 17;
        const int j  = tid - fr * 17;
        const float* wrow = (j < K) ? (ck_w + (size_t)j * FD)
                                    : ((j == K) ? fg_w : gg_w);
        const float4* w4 = (const float4*)wrow;
        const float4* f4 = (const float4*)&sf[fr][0];
        float4 acc = make_float4(0.f, 0.f, 0.f, 0.f);
        #pragma unroll
        for (int i = 0; i < FD / 4; ++i) {
            const float4 a = f4[i];
            const float4 w = w4[i];
            acc.x += a.x * w.x; acc.y += a.y * w.y;
            acc.z += a.z * w.z; acc.w += a.w * w.w;
        }
        const float bias = (j < K) ? ck_b[j] : ((j == K) ? fg_b[0] : gg_b[0]);
        sdots[fr][j] = acc.x + acc.y + acc.z + acc.w + bias;
    }
    __syncthreads();

    // ---- phase C: per-frame params ----
    if (tid < NFR) {
        const int pf = f0 - 1 + tid;
        if (pf < 0) {
            #pragma unroll
            for (int k = 0; k < 16; ++k) sfk[tid][k] = 0.f;  // zero prev => tail 0
        } else {
            float kern[K];
            float n2 = 0.f;
            #pragma unroll
            for (int k = 0; k < K; ++k) {
                kern[k] = sdots[tid][k];
                n2 += kern[k] * kern[k];
            }
            const float inv   = 1.f / (1e-6f + sqrtf(n2));
            const float gain  = expf(-fmaxf(sdots[tid][K], 0.f) + LOG_GAIN_LIMIT);
            const float ggain = expf(GAIN_A * tanhf(sdots[tid][K + 1]));
            const float ks    = ggain * gain * inv;
            #pragma unroll
            for (int k = 0; k < K; ++k) sfk[tid][k] = ks * kern[k];
            sfk[tid][15] = ggain;
        }
    }
    __syncthreads();

    // ---- phase D: conv + crossfade, 4 outputs per thread, all 16B ops ----
    const int obase = f0 * FS;
    for (int g = tid; g < FPB * (FS / 4); g += 256) {
        const int frl = g / (FS / 4);        // 0..FPB-1
        const int gi  = g - frl * (FS / 4);  // 0..39
        const int t   = gi * 4;
        const int fr  = frl + 1;

        const float4 k0 = *(const float4*)&sfk[fr][0];
        const float4 k1 = *(const float4*)&sfk[fr][4];
        const float4 k2 = *(const float4*)&sfk[fr][8];
        const float4 k3 = *(const float4*)&sfk[fr][12];
        const float kc[16] = {k0.x,k0.y,k0.z,k0.w, k1.x,k1.y,k1.z,k1.w,
                              k2.x,k2.y,k2.z,k2.w, k3.x,k3.y,k3.z,k3.w};

        float w[20];
        #pragma unroll
        for (int q = 0; q < 5; ++q)
            *(float4*)&w[4 * q] = *(const float4*)&swin[fr][t + 4 * q];

        const float4 pt = *(const float4*)(xb + obase + frl * FS + t);

        float4 res;
        {
            float c0 = 0.f, c1 = 0.f, c2 = 0.f, c3 = 0.f;
            #pragma unroll
            for (int k = 0; k < K; ++k) {
                const float kk = kc[k];
                c0 += w[k]     * kk;
                c1 += w[k + 1] * kk;
                c2 += w[k + 2] * kk;
                c3 += w[k + 3] * kk;
            }
            const float ps = kc[15];
            res.x = c0 + ps * pt.x; res.y = c1 + ps * pt.y;
            res.z = c2 + ps * pt.z; res.w = c3 + ps * pt.w;
        }

        if (gi < OV / 4) {   // head: crossfade with previous frame tail
            const float4 q0 = *(const float4*)&sfk[fr - 1][0];
            const float4 q1 = *(const float4*)&sfk[fr - 1][4];
            const float4 q2 = *(const float4*)&sfk[fr - 1][8];
            const float4 q3 = *(const float4*)&sfk[fr - 1][12];
            const float qc[16] = {q0.x,q0.y,q0.z,q0.w, q1.x,q1.y,q1.z,q1.w,
                                  q2.x,q2.y,q2.z,q2.w, q3.x,q3.y,q3.z,q3.w};
            float wv[20];
            #pragma unroll
            for (int q = 0; q < 5; ++q)
                *(float4*)&wv[4 * q] = *(const float4*)&swin[fr - 1][FS + t + 4 * q];

            float c0 = 0.f, c1 = 0.f, c2 = 0.f, c3 = 0.f;
            #pragma unroll
            for (int k = 0; k < K; ++k) {
                const float kk = qc[k];
                c0 += wv[k]     * kk;
                c1 += wv[k + 1] * kk;
                c2 += wv[k + 2] * kk;
                c3 += wv[k + 3] * kk;
            }
            const float ps = qc[15];
            const float4 tail = make_float4(c0 + ps * pt.x, c1 + ps * pt.y,
                                            c2 + ps * pt.z, c3 + ps * pt.w);
            const float4 w2 = *(const float4*)&swin2[t];
            res.x = res.x * (1.f - w2.x) + tail.x * w2.x;
            res.y = res.y * (1.f - w2.y) + tail.y * w2.y;
            res.z = res.z * (1.f - w2.z) + tail.z * w2.z;
            res.w = res.w * (1.f - w2.w) + tail.w * w2.w;
        }

        *(float4*)(out + (size_t)b * NSAMP + obase + frl * FS + t) = res;
    }
}

extern "C" void kernel_launch(void* const* d_in, const int* in_sizes, int n_in,
                              void* d_out, int out_size, void* d_ws, size_t ws_size,
                              hipStream_t stream) {
    const float* x    = (const float*)d_in[0];
    const float* feat = (const float*)d_in[1];
    const int*   lags = (const int*)d_in[2];
    const float* ck_w = (const float*)d_in[3];
    const float* ck_b = (const float*)d_in[4];
    const float* fg_w = (const float*)d_in[5];
    const float* fg_b = (const float*)d_in[6];
    const float* gg_w = (const float*)d_in[7];
    const float* gg_b = (const float*)d_in[8];
    float* out = (float*)d_out;

    const int B = in_sizes[0] / NSAMP;
    const int nblocks = B * (NFRAMES / FPB);
    comb_fused<<<dim3(nblocks), dim3(256), 0, stream>>>(
        x, feat, lags, ck_w, ck_b, fg_w, fg_b, gg_w, gg_b, out);
}